// Round 8
// baseline (1339.987 us; speedup 1.0000x reference)
//
#include <hip/hip_runtime.h>

#define N_PTS 4096
#define B_SZ  8
#define M_OUT 1024
#define NS    64
#define CIN   128
#define COUT  256

typedef float v2f __attribute__((ext_vector_type(2)));

// Wave-64 max reduce via DPP (row_shr 1/2/4/8, bcast15, bcast31), result
// broadcast through readlane(63). Bit-exact fmax tree. HW-VALIDATED (v2 776us
// and R6 738us passing runs).
__device__ __forceinline__ float dpp_max_f32(float v) {
  int x = __builtin_bit_cast(int, v);
#define STG(C)                                                              \
  {                                                                         \
    int y = __builtin_amdgcn_update_dpp(x, x, C, 0xF, 0xF, false);          \
    float a = __builtin_bit_cast(float, x);                                 \
    float b2 = __builtin_bit_cast(float, y);                                \
    a = fmaxf(a, b2);                                                       \
    x = __builtin_bit_cast(int, a);                                         \
  }
  STG(0x111) STG(0x112) STG(0x114) STG(0x118) STG(0x142) STG(0x143)
#undef STG
  return __builtin_bit_cast(float, __builtin_amdgcn_readlane(x, 63));
}

// ---------------------------------------------------------------------------
// 1) Furthest point sampling — one block of 512 threads (8 waves = 2/SIMD so
//    one wave's issue hides the other's DPP/LDS/chain stalls; R6 at 1 wave/
//    SIMD measured 45% VALU-busy on active CUs = stall-dominated).
//    SINGLE change vs the PASSING R6 kernel: thread count. Everything else
//    identical: CONTIGUOUS mapping (thread t owns [8t, 8t+8) as 4 packed
//    float2; lane/wave order == index order so argmax tie-break stays
//    structural), in-scan strict-> local argmax, DPP value ladder,
//    ballot -> s_ff1 -> readlane argmax, pre-barrier uniform LDS coord read,
//    ONE parity-buffered barrier, slot combine (now 8 slots), LDS winner
//    staging. Tie-break: lower index wins everywhere (matches jnp.argmax).
// ---------------------------------------------------------------------------
__global__ __launch_bounds__(512) void fps_kernel(const float* __restrict__ xyz,
                                                  int* __restrict__ fps_idx) {
#pragma clang fp contract(off)
  __shared__ float lx[N_PTS], ly[N_PTS], lz[N_PTS];
  __shared__ float4 sl[2][8];   // per-wave {val, x, y, z}
  __shared__ int    siw[2][8];  // per-wave winner idx
  __shared__ int    wlds[M_OUT];
  const int b = blockIdx.x, t = threadIdx.x;
  const int lane = t & 63, wv = t >> 6;
  const float* base = xyz + b * N_PTS * 3;
  for (int e = t; e < N_PTS; e += 512) {
    lx[e] = base[e * 3 + 0];
    ly[e] = base[e * 3 + 1];
    lz[e] = base[e * 3 + 2];
  }
  __syncthreads();
  const int nb = t * 8;  // this thread's contiguous index base
  v2f px[4], py[4], pz[4], m2[4];
#pragma unroll
  for (int j = 0; j < 4; ++j) {
    int n0 = nb + 2 * j;
    px[j] = (v2f){lx[n0], lx[n0 + 1]};
    py[j] = (v2f){ly[n0], ly[n0 + 1]};
    pz[j] = (v2f){lz[n0], lz[n0 + 1]};
    m2[j] = (v2f){1e10f, 1e10f};
  }
  int cur = 0;
  float cx = lx[0], cy = ly[0], cz = lz[0];
  for (int i = 0; i < M_OUT; ++i) {
    if (t == 0) wlds[i] = cur;
    float bv = -1.0f;
    int bj = 0;  // local slot 0..7 (inline-const cndmask updates)
#pragma unroll
    for (int j = 0; j < 4; ++j) {
      v2f dx = px[j] - cx, dy = py[j] - cy, dz = pz[j] - cz;
      v2f d = dx * dx + dy * dy;  // contract(off): numpy op order, no FMA
      d = d + dz * dz;
      v2f md = __builtin_elementwise_min(m2[j], d);
      m2[j] = md;
      // ascending j, strict > => lowest tied index within the thread
      if (md.x > bv) { bv = md.x; bj = 2 * j; }
      if (md.y > bv) { bv = md.y; bj = 2 * j + 1; }
    }
    const float mv = dpp_max_f32(bv);  // wave max, all lanes (validated)
    // Wave argmax: lowest tied lane holds the lowest tied global index.
    unsigned long long tied = __ballot(bv == mv);  // non-empty by construction
    const int fl = __ffsll(tied) - 1;              // first tied lane (SGPR)
    const int bi = nb + bj;                        // own candidate global idx
    const int widx = __builtin_amdgcn_readlane(bi, fl);
    // Pre-barrier uniform-address LDS broadcast read of winner coords;
    // latency hides in barrier arrival skew / the sibling wave's issue.
    const float wx = lx[widx], wy = ly[widx], wz = lz[widx];
    const int p = i & 1;
    if (lane == 0) {
      sl[p][wv] = make_float4(mv, wx, wy, wz);
      siw[p][wv] = widx;
    }
    __syncthreads();  // the only barrier per step (slots parity-buffered)
    float4 s0 = sl[p][0];
    float gv = s0.x, gx = s0.y, gy = s0.z, gz = s0.w;
    int gi = siw[p][0];
#pragma unroll
    for (int w = 1; w < 8; ++w) {
      float4 s = sl[p][w];
      int ii = siw[p][w];
      bool bt = (s.x > gv) || (s.x == gv && ii < gi);
      gv = bt ? s.x : gv;
      gi = bt ? ii : gi;
      gx = bt ? s.y : gx;
      gy = bt ? s.z : gy;
      gz = bt ? s.w : gz;
    }
    cur = gi; cx = gx; cy = gy; cz = gz;
  }
  __syncthreads();
  for (int e = t; e < M_OUT; e += 512) fps_idx[b * M_OUT + e] = wlds[e];
}

// ---------------------------------------------------------------------------
// 2) Ball query — one wave per (b, m). Ordered compaction over n via ballot +
//    prefix popcount; first NS in-ball indices in ascending order, padded with
//    the first hit. Strict d2 < r^2 in un-contracted f32 (matches reference).
// ---------------------------------------------------------------------------
__global__ __launch_bounds__(256) void ballq_kernel(const float* __restrict__ xyz,
                                                    const int* __restrict__ fps_idx,
                                                    int* __restrict__ idx_out) {
#pragma clang fp contract(off)
  const int p = blockIdx.x * 4 + (threadIdx.x >> 6);
  const int lane = threadIdx.x & 63;
  const int b = p >> 10;
  const float* base = xyz + b * N_PTS * 3;
  const int cidx = fps_idx[p];
  const float cx = base[cidx * 3 + 0], cy = base[cidx * 3 + 1], cz = base[cidx * 3 + 2];
  int* out = idx_out + p * NS;
  int cnt = 0, first = 0;
  for (int c = 0; c < N_PTS / 64 && cnt < NS; ++c) {
    const int n = c * 64 + lane;
    float dx = base[n * 3 + 0] - cx;
    float dy = base[n * 3 + 1] - cy;
    float dz = base[n * 3 + 2] - cz;
    float d = dx * dx + dy * dy;
    d = d + dz * dz;
    const bool inb = d < 0.1024f;  // f32(RADIUS^2), matches JAX weak-scalar promotion
    unsigned long long mask = __ballot(inb);
    if (cnt == 0 && mask) first = c * 64 + (__ffsll(mask) - 1);
    const int pos = cnt + __popcll(mask & ((1ull << lane) - 1ull));
    if (inb && pos < NS) out[pos] = n;
    cnt += (int)__popcll(mask);
  }
  if (lane >= cnt) out[lane] = first;  // pad (center itself guarantees cnt >= 1)
}

// ---------------------------------------------------------------------------
// 3) Pointwise conv on ALL 4096 points (conv commutes with gather): per batch
//    Z[n,o] = sum_c F[c,n] * W[o,c].  Tiled 64n x 64o, BK=32, 4x4 microtile.
//    Z stored [B][N][O] so the pool gather is coalesced across o-lanes.
// ---------------------------------------------------------------------------
__global__ __launch_bounds__(256) void conv_kernel(const float* __restrict__ F,
                                                   const float* __restrict__ W,
                                                   float* __restrict__ Z) {
  __shared__ float Bs[CIN][64 + 4];  // [c][o]
  __shared__ float As[32][64 + 4];   // [c][n]
  const int b = blockIdx.z;
  const int n0 = blockIdx.x * 64, o0 = blockIdx.y * 64;
  const int tid = threadIdx.x;
  for (int l = 0; l < 32; ++l) {
    int e = l * 256 + tid;
    int c = e & 127, oo = e >> 7;
    Bs[c][oo] = W[(o0 + oo) * CIN + c];
  }
  float acc[4][4] = {};
  const int tx = tid & 15, ty = tid >> 4;
  const float* Fb = F + b * CIN * N_PTS;
  for (int c0 = 0; c0 < CIN; c0 += 32) {
    __syncthreads();
    for (int l = 0; l < 8; ++l) {
      int e = l * 256 + tid;
      int nn = e & 63, cc = e >> 6;
      As[cc][nn] = Fb[(c0 + cc) * N_PTS + n0 + nn];
    }
    __syncthreads();
#pragma unroll
    for (int cc = 0; cc < 32; ++cc) {
      float4 a = *(const float4*)&As[cc][tx * 4];
      float4 w4 = *(const float4*)&Bs[c0 + cc][ty * 4];
      acc[0][0] += a.x * w4.x; acc[0][1] += a.x * w4.y; acc[0][2] += a.x * w4.z; acc[0][3] += a.x * w4.w;
      acc[1][0] += a.y * w4.x; acc[1][1] += a.y * w4.y; acc[1][2] += a.y * w4.z; acc[1][3] += a.y * w4.w;
      acc[2][0] += a.z * w4.x; acc[2][1] += a.z * w4.y; acc[2][2] += a.z * w4.z; acc[2][3] += a.z * w4.w;
      acc[3][0] += a.w * w4.x; acc[3][1] += a.w * w4.y; acc[3][2] += a.w * w4.z; acc[3][3] += a.w * w4.w;
    }
  }
  float* Zb = Z + (size_t)(b * N_PTS + n0) * COUT + o0;
#pragma unroll
  for (int i = 0; i < 4; ++i) {
    int nn = tx * 4 + i;
    float4 v = make_float4(acc[i][0], acc[i][1], acc[i][2], acc[i][3]);
    *(float4*)&Zb[(size_t)nn * COUT + ty * 4] = v;
  }
}

// ---------------------------------------------------------------------------
// 4) Gather + max-pool + BN + ReLU. max commutes with the (positive-scale)
//    monotone affine + relu, so pool raw conv outputs then apply epilogue once.
// ---------------------------------------------------------------------------
__global__ __launch_bounds__(256) void pool_kernel(const float* __restrict__ Z,
                                                   const int* __restrict__ idx,
                                                   const float* __restrict__ bias,
                                                   const float* __restrict__ gamma,
                                                   const float* __restrict__ beta,
                                                   const float* __restrict__ rmean,
                                                   const float* __restrict__ rvar,
                                                   float* __restrict__ out) {
  __shared__ float T[COUT][17];
  const int b = blockIdx.x >> 6;
  const int m0 = (blockIdx.x & 63) * 16;
  const int o = threadIdx.x;
  const float sc = gamma[o] * (1.0f / sqrtf(rvar[o] + 1e-5f));
  const float bo = bias[o], mo = rmean[o], bt = beta[o];
  const float* Zb = Z + (size_t)b * N_PTS * COUT;
  const int* ib = idx + (size_t)(b * M_OUT + m0) * NS;
  for (int mi = 0; mi < 16; ++mi) {
    float best = -1e30f;
#pragma unroll 4
    for (int s = 0; s < NS; ++s) {
      int n = ib[mi * NS + s];
      best = fmaxf(best, Zb[(size_t)n * COUT + o]);
    }
    float t = best + bo;
    t = (t - mo) * sc + bt;
    T[o][mi] = fmaxf(t, 0.0f);
  }
  __syncthreads();
  for (int l = 0; l < 16; ++l) {
    int e = l * 256 + (int)threadIdx.x;
    int mm = e & 15, oo = e >> 4;
    out[(size_t)(b * COUT + oo) * M_OUT + m0 + mm] = T[oo][mm];
  }
}

extern "C" void kernel_launch(void* const* d_in, const int* in_sizes, int n_in,
                              void* d_out, int out_size, void* d_ws, size_t ws_size,
                              hipStream_t stream) {
  const float* xyz      = (const float*)d_in[0];
  const float* features = (const float*)d_in[1];
  const float* W        = (const float*)d_in[2];
  const float* bias     = (const float*)d_in[3];
  const float* gamma    = (const float*)d_in[4];
  const float* beta     = (const float*)d_in[5];
  const float* rmean    = (const float*)d_in[6];
  const float* rvar     = (const float*)d_in[7];
  float* out = (float*)d_out;

  char* ws = (char*)d_ws;
  int* fps  = (int*)ws;                                  // 32 KB
  int* bidx = (int*)(ws + (64 << 10));                   // 2 MB
  float* Z  = (float*)(ws + (64 << 10) + (2 << 20));     // 33.5 MB

  fps_kernel<<<B_SZ, 512, 0, stream>>>(xyz, fps);
  ballq_kernel<<<(B_SZ * M_OUT) / 4, 256, 0, stream>>>(xyz, fps, bidx);
  conv_kernel<<<dim3(N_PTS / 64, COUT / 64, B_SZ), 256, 0, stream>>>(features, W, Z);
  pool_kernel<<<B_SZ * (M_OUT / 16), 256, 0, stream>>>(Z, bidx, bias, gamma, beta, rmean, rvar, out);
}

// Round 9
// 862.050 us; speedup vs baseline: 1.5544x; 1.5544x over previous
//
#include <hip/hip_runtime.h>

#define N_PTS 4096
#define B_SZ  8
#define M_OUT 1024
#define NS    64
#define CIN   128
#define COUT  256

typedef float v2f __attribute__((ext_vector_type(2)));

// Wave-64 max reduce via DPP (row_shr 1/2/4/8, bcast15, bcast31), result
// broadcast through readlane(63). Bit-exact fmax tree. HW-VALIDATED (v2 776us
// and R6 738us passing runs).
__device__ __forceinline__ float dpp_max_f32(float v) {
  int x = __builtin_bit_cast(int, v);
#define STG(C)                                                              \
  {                                                                         \
    int y = __builtin_amdgcn_update_dpp(x, x, C, 0xF, 0xF, false);          \
    float a = __builtin_bit_cast(float, x);                                 \
    float b2 = __builtin_bit_cast(float, y);                                \
    a = fmaxf(a, b2);                                                       \
    x = __builtin_bit_cast(int, a);                                         \
  }
  STG(0x111) STG(0x112) STG(0x114) STG(0x118) STG(0x142) STG(0x143)
#undef STG
  return __builtin_bit_cast(float, __builtin_amdgcn_readlane(x, 63));
}

// ---------------------------------------------------------------------------
// 1) FUSED fps + conv. Blocks 0..7: the R6-validated FPS (738us, 256 thr,
//    4 waves — measured local optimum in wave count; R7 showed more waves
//    only replicate the serial reduce stages). Blocks 8..2055: the pointwise
//    conv (independent inputs: features/W vs xyz — no sync needed). conv
//    overlaps FPS's 740us window on the other ~248 CUs instead of running
//    serially after it. Shared memory is a union of the two layouts (53.4KB,
//    2 blocks/CU). FPS body is byte-for-byte the R6 logic.
// ---------------------------------------------------------------------------
__global__ __launch_bounds__(256) void fps_conv_kernel(
    const float* __restrict__ xyz, int* __restrict__ fps_idx,
    const float* __restrict__ F, const float* __restrict__ W,
    float* __restrict__ Z) {
  __shared__ __align__(16) float smem[13360];
  if (blockIdx.x < 8) {
#pragma clang fp contract(off)
    // ---- FPS (R6-validated) ----
    float* lx = smem;                         // [4096]
    float* ly = smem + 4096;                  // [4096]
    float* lz = smem + 8192;                  // [4096]
    float4 (*sl)[4] = (float4(*)[4])(smem + 12288);  // [2][4]
    int (*siw)[4] = (int(*)[4])(smem + 12320);       // [2][4]
    int* wlds = (int*)(smem + 12328);                // [1024]
    const int b = blockIdx.x, t = threadIdx.x;
    const int lane = t & 63, wv = t >> 6;
    const float* base = xyz + b * N_PTS * 3;
    for (int e = t; e < N_PTS; e += 256) {
      lx[e] = base[e * 3 + 0];
      ly[e] = base[e * 3 + 1];
      lz[e] = base[e * 3 + 2];
    }
    __syncthreads();
    const int nb = t * 16;  // contiguous: thread t owns [16t, 16t+16)
    v2f px[8], py[8], pz[8], m2[8];
#pragma unroll
    for (int j = 0; j < 8; ++j) {
      int n0 = nb + 2 * j;
      px[j] = (v2f){lx[n0], lx[n0 + 1]};
      py[j] = (v2f){ly[n0], ly[n0 + 1]};
      pz[j] = (v2f){lz[n0], lz[n0 + 1]};
      m2[j] = (v2f){1e10f, 1e10f};
    }
    int cur = 0;
    float cx = lx[0], cy = ly[0], cz = lz[0];
    for (int i = 0; i < M_OUT; ++i) {
      if (t == 0) wlds[i] = cur;
      float bv = -1.0f;
      int bj = 0;
#pragma unroll
      for (int j = 0; j < 8; ++j) {
        v2f dx = px[j] - cx, dy = py[j] - cy, dz = pz[j] - cz;
        v2f d = dx * dx + dy * dy;  // contract(off): numpy op order, no FMA
        d = d + dz * dz;
        v2f md = __builtin_elementwise_min(m2[j], d);
        m2[j] = md;
        // ascending j, strict > => lowest tied index within the thread
        if (md.x > bv) { bv = md.x; bj = 2 * j; }
        if (md.y > bv) { bv = md.y; bj = 2 * j + 1; }
      }
      const float mv = dpp_max_f32(bv);  // wave max, all lanes (validated)
      unsigned long long tied = __ballot(bv == mv);  // non-empty
      const int fl = __ffsll(tied) - 1;              // first tied lane
      const int bi = nb + bj;
      const int widx = __builtin_amdgcn_readlane(bi, fl);
      // Pre-barrier uniform LDS broadcast read; hides in barrier skew.
      const float wx = lx[widx], wy = ly[widx], wz = lz[widx];
      const int p = i & 1;
      if (lane == 0) {
        sl[p][wv] = make_float4(mv, wx, wy, wz);
        siw[p][wv] = widx;
      }
      __syncthreads();  // the only barrier per step (parity-buffered slots)
      float4 s0 = sl[p][0], s1 = sl[p][1], s2 = sl[p][2], s3 = sl[p][3];
      int i0 = siw[p][0], i1 = siw[p][1], i2 = siw[p][2], i3 = siw[p][3];
      float gv = s0.x, gx = s0.y, gy = s0.z, gz = s0.w;
      int gi = i0;
      bool bt;
      bt = (s1.x > gv) || (s1.x == gv && i1 < gi);
      if (bt) { gv = s1.x; gi = i1; gx = s1.y; gy = s1.z; gz = s1.w; }
      bt = (s2.x > gv) || (s2.x == gv && i2 < gi);
      if (bt) { gv = s2.x; gi = i2; gx = s2.y; gy = s2.z; gz = s2.w; }
      bt = (s3.x > gv) || (s3.x == gv && i3 < gi);
      if (bt) { gv = s3.x; gi = i3; gx = s3.y; gy = s3.z; gz = s3.w; }
      cur = gi; cx = gx; cy = gy; cz = gz;
    }
    __syncthreads();
    for (int e = t; e < M_OUT; e += 256) fps_idx[b * M_OUT + e] = wlds[e];
  } else {
    // ---- conv: Z[b][n][o] = sum_c F[b][c][n] * W[o][c] (default contract:
    // FMA ok, tolerance is loose and GEMM order is free) ----
    float (*Bs)[68] = (float(*)[68])smem;          // [128][68]
    float (*As)[68] = (float(*)[68])(smem + 8704); // [32][68]
    const int bid = blockIdx.x - 8;
    const int n0 = (bid & 63) * 64;
    const int o0 = ((bid >> 6) & 3) * 64;
    const int b = bid >> 8;
    const int tid = threadIdx.x;
    for (int l = 0; l < 32; ++l) {
      int e = l * 256 + tid;
      int c = e & 127, oo = e >> 7;
      Bs[c][oo] = W[(o0 + oo) * CIN + c];
    }
    float acc[4][4] = {};
    const int tx = tid & 15, ty = tid >> 4;
    const float* Fb = F + b * CIN * N_PTS;
    for (int c0 = 0; c0 < CIN; c0 += 32) {
      __syncthreads();
      for (int l = 0; l < 8; ++l) {
        int e = l * 256 + tid;
        int nn = e & 63, cc = e >> 6;
        As[cc][nn] = Fb[(c0 + cc) * N_PTS + n0 + nn];
      }
      __syncthreads();
#pragma unroll
      for (int cc = 0; cc < 32; ++cc) {
        float4 a = *(const float4*)&As[cc][tx * 4];
        float4 w4 = *(const float4*)&Bs[c0 + cc][ty * 4];
        acc[0][0] += a.x * w4.x; acc[0][1] += a.x * w4.y; acc[0][2] += a.x * w4.z; acc[0][3] += a.x * w4.w;
        acc[1][0] += a.y * w4.x; acc[1][1] += a.y * w4.y; acc[1][2] += a.y * w4.z; acc[1][3] += a.y * w4.w;
        acc[2][0] += a.z * w4.x; acc[2][1] += a.z * w4.y; acc[2][2] += a.z * w4.z; acc[2][3] += a.z * w4.w;
        acc[3][0] += a.w * w4.x; acc[3][1] += a.w * w4.y; acc[3][2] += a.w * w4.z; acc[3][3] += a.w * w4.w;
      }
    }
    float* Zb = Z + (size_t)(b * N_PTS + n0) * COUT + o0;
#pragma unroll
    for (int i = 0; i < 4; ++i) {
      int nn = tx * 4 + i;
      float4 v = make_float4(acc[i][0], acc[i][1], acc[i][2], acc[i][3]);
      *(float4*)&Zb[(size_t)nn * COUT + ty * 4] = v;
    }
  }
}

// ---------------------------------------------------------------------------
// 2) Ball query — unchanged (validated since R0).
// ---------------------------------------------------------------------------
__global__ __launch_bounds__(256) void ballq_kernel(const float* __restrict__ xyz,
                                                    const int* __restrict__ fps_idx,
                                                    int* __restrict__ idx_out) {
#pragma clang fp contract(off)
  const int p = blockIdx.x * 4 + (threadIdx.x >> 6);
  const int lane = threadIdx.x & 63;
  const int b = p >> 10;
  const float* base = xyz + b * N_PTS * 3;
  const int cidx = fps_idx[p];
  const float cx = base[cidx * 3 + 0], cy = base[cidx * 3 + 1], cz = base[cidx * 3 + 2];
  int* out = idx_out + p * NS;
  int cnt = 0, first = 0;
  for (int c = 0; c < N_PTS / 64 && cnt < NS; ++c) {
    const int n = c * 64 + lane;
    float dx = base[n * 3 + 0] - cx;
    float dy = base[n * 3 + 1] - cy;
    float dz = base[n * 3 + 2] - cz;
    float d = dx * dx + dy * dy;
    d = d + dz * dz;
    const bool inb = d < 0.1024f;  // f32(RADIUS^2)
    unsigned long long mask = __ballot(inb);
    if (cnt == 0 && mask) first = c * 64 + (__ffsll(mask) - 1);
    const int pos = cnt + __popcll(mask & ((1ull << lane) - 1ull));
    if (inb && pos < NS) out[pos] = n;
    cnt += (int)__popcll(mask);
  }
  if (lane >= cnt) out[lane] = first;  // pad
}

// ---------------------------------------------------------------------------
// 3) Gather + max-pool + BN + ReLU. m-tile 8 (1024 blocks = 4/CU, 16 waves/CU
//    for gather-latency hiding). Neighbor indices staged in LDS once per block
//    (kills 64 uniform global idx loads per mi), read back as int4; 4
//    independent max chains break the 64-deep load->fmax dependency.
// ---------------------------------------------------------------------------
__global__ __launch_bounds__(256) void pool_kernel(const float* __restrict__ Z,
                                                   const int* __restrict__ idx,
                                                   const float* __restrict__ bias,
                                                   const float* __restrict__ gamma,
                                                   const float* __restrict__ beta,
                                                   const float* __restrict__ rmean,
                                                   const float* __restrict__ rvar,
                                                   float* __restrict__ out) {
  __shared__ float T[COUT][9];
  __shared__ __align__(16) int sidx[8 * NS];
  const int b = blockIdx.x >> 7;           // 128 m-tiles of 8 per batch
  const int m0 = (blockIdx.x & 127) * 8;
  const int o = threadIdx.x;
  const int* ib = idx + (size_t)(b * M_OUT + m0) * NS;  // 512 ints
  sidx[o] = ib[o];
  sidx[o + 256] = ib[o + 256];
  const float sc = gamma[o] * (1.0f / sqrtf(rvar[o] + 1e-5f));
  const float bo = bias[o], mo = rmean[o], bt = beta[o];
  const float* Zb = Z + (size_t)b * N_PTS * COUT;
  __syncthreads();
  for (int mi = 0; mi < 8; ++mi) {
    float b0 = -1e30f, b1 = -1e30f, b2 = -1e30f, b3 = -1e30f;
#pragma unroll
    for (int s = 0; s < NS; s += 4) {
      int4 iv = *(const int4*)&sidx[mi * NS + s];
      b0 = fmaxf(b0, Zb[(size_t)iv.x * COUT + o]);
      b1 = fmaxf(b1, Zb[(size_t)iv.y * COUT + o]);
      b2 = fmaxf(b2, Zb[(size_t)iv.z * COUT + o]);
      b3 = fmaxf(b3, Zb[(size_t)iv.w * COUT + o]);
    }
    float best = fmaxf(fmaxf(b0, b1), fmaxf(b2, b3));
    float t = best + bo;
    t = (t - mo) * sc + bt;
    T[o][mi] = fmaxf(t, 0.0f);
  }
  __syncthreads();
  for (int l = 0; l < 8; ++l) {
    int e = l * 256 + (int)threadIdx.x;
    int mm = e & 7, oo = e >> 3;
    out[(size_t)(b * COUT + oo) * M_OUT + m0 + mm] = T[oo][mm];
  }
}

extern "C" void kernel_launch(void* const* d_in, const int* in_sizes, int n_in,
                              void* d_out, int out_size, void* d_ws, size_t ws_size,
                              hipStream_t stream) {
  const float* xyz      = (const float*)d_in[0];
  const float* features = (const float*)d_in[1];
  const float* W        = (const float*)d_in[2];
  const float* bias     = (const float*)d_in[3];
  const float* gamma    = (const float*)d_in[4];
  const float* beta     = (const float*)d_in[5];
  const float* rmean    = (const float*)d_in[6];
  const float* rvar     = (const float*)d_in[7];
  float* out = (float*)d_out;

  char* ws = (char*)d_ws;
  int* fps  = (int*)ws;                                  // 32 KB
  int* bidx = (int*)(ws + (64 << 10));                   // 2 MB
  float* Z  = (float*)(ws + (64 << 10) + (2 << 20));     // 33.5 MB

  fps_conv_kernel<<<8 + 2048, 256, 0, stream>>>(xyz, fps, features, W, Z);
  ballq_kernel<<<(B_SZ * M_OUT) / 4, 256, 0, stream>>>(xyz, fps, bidx);
  pool_kernel<<<B_SZ * (M_OUT / 8), 256, 0, stream>>>(Z, bidx, bias, gamma, beta, rmean, rvar, out);
}

// Round 10
// 849.228 us; speedup vs baseline: 1.5779x; 1.0151x over previous
//
#include <hip/hip_runtime.h>

#define N_PTS 4096
#define B_SZ  8
#define M_OUT 1024
#define NS    64
#define CIN   128
#define COUT  256

typedef float v2f __attribute__((ext_vector_type(2)));

// Wave-64 max reduce via DPP (row_shr 1/2/4/8, bcast15, bcast31), result
// broadcast through readlane(63). Bit-exact fmax tree. HW-VALIDATED (v2 776us,
// R6 738us, R8 728us passing runs).
__device__ __forceinline__ float dpp_max_f32(float v) {
  int x = __builtin_bit_cast(int, v);
#define STG(C)                                                              \
  {                                                                         \
    int y = __builtin_amdgcn_update_dpp(x, x, C, 0xF, 0xF, false);          \
    float a = __builtin_bit_cast(float, x);                                 \
    float b2 = __builtin_bit_cast(float, y);                                \
    a = fmaxf(a, b2);                                                       \
    x = __builtin_bit_cast(int, a);                                         \
  }
  STG(0x111) STG(0x112) STG(0x114) STG(0x118) STG(0x142) STG(0x143)
#undef STG
  return __builtin_bit_cast(float, __builtin_amdgcn_readlane(x, 63));
}

// ---------------------------------------------------------------------------
// 1) FUSED fps + conv (R8-validated, 728us: conv rides inside the FPS window
//    on the other ~248 CUs; independent inputs, no sync). FPS body is the
//    R6-validated 256-thread code — measured local optimum (R7: more waves
//    only replicate the serial reduce stages, +155cyc/wave/step).
// ---------------------------------------------------------------------------
__global__ __launch_bounds__(256) void fps_conv_kernel(
    const float* __restrict__ xyz, int* __restrict__ fps_idx,
    const float* __restrict__ F, const float* __restrict__ W,
    float* __restrict__ Z) {
  __shared__ __align__(16) float smem[13360];
  if (blockIdx.x < 8) {
#pragma clang fp contract(off)
    // ---- FPS (R6-validated) ----
    float* lx = smem;                         // [4096]
    float* ly = smem + 4096;                  // [4096]
    float* lz = smem + 8192;                  // [4096]
    float4 (*sl)[4] = (float4(*)[4])(smem + 12288);  // [2][4]
    int (*siw)[4] = (int(*)[4])(smem + 12320);       // [2][4]
    int* wlds = (int*)(smem + 12328);                // [1024]
    const int b = blockIdx.x, t = threadIdx.x;
    const int lane = t & 63, wv = t >> 6;
    const float* base = xyz + b * N_PTS * 3;
    for (int e = t; e < N_PTS; e += 256) {
      lx[e] = base[e * 3 + 0];
      ly[e] = base[e * 3 + 1];
      lz[e] = base[e * 3 + 2];
    }
    __syncthreads();
    const int nb = t * 16;  // contiguous: thread t owns [16t, 16t+16)
    v2f px[8], py[8], pz[8], m2[8];
#pragma unroll
    for (int j = 0; j < 8; ++j) {
      int n0 = nb + 2 * j;
      px[j] = (v2f){lx[n0], lx[n0 + 1]};
      py[j] = (v2f){ly[n0], ly[n0 + 1]};
      pz[j] = (v2f){lz[n0], lz[n0 + 1]};
      m2[j] = (v2f){1e10f, 1e10f};
    }
    int cur = 0;
    float cx = lx[0], cy = ly[0], cz = lz[0];
    for (int i = 0; i < M_OUT; ++i) {
      if (t == 0) wlds[i] = cur;
      float bv = -1.0f;
      int bj = 0;
#pragma unroll
      for (int j = 0; j < 8; ++j) {
        v2f dx = px[j] - cx, dy = py[j] - cy, dz = pz[j] - cz;
        v2f d = dx * dx + dy * dy;  // contract(off): numpy op order, no FMA
        d = d + dz * dz;
        v2f md = __builtin_elementwise_min(m2[j], d);
        m2[j] = md;
        // ascending j, strict > => lowest tied index within the thread
        if (md.x > bv) { bv = md.x; bj = 2 * j; }
        if (md.y > bv) { bv = md.y; bj = 2 * j + 1; }
      }
      const float mv = dpp_max_f32(bv);  // wave max, all lanes (validated)
      unsigned long long tied = __ballot(bv == mv);  // non-empty
      const int fl = __ffsll(tied) - 1;              // first tied lane
      const int bi = nb + bj;
      const int widx = __builtin_amdgcn_readlane(bi, fl);
      // Pre-barrier uniform LDS broadcast read; hides in barrier skew.
      const float wx = lx[widx], wy = ly[widx], wz = lz[widx];
      const int p = i & 1;
      if (lane == 0) {
        sl[p][wv] = make_float4(mv, wx, wy, wz);
        siw[p][wv] = widx;
      }
      __syncthreads();  // the only barrier per step (parity-buffered slots)
      float4 s0 = sl[p][0], s1 = sl[p][1], s2 = sl[p][2], s3 = sl[p][3];
      int i0 = siw[p][0], i1 = siw[p][1], i2 = siw[p][2], i3 = siw[p][3];
      float gv = s0.x, gx = s0.y, gy = s0.z, gz = s0.w;
      int gi = i0;
      bool bt;
      bt = (s1.x > gv) || (s1.x == gv && i1 < gi);
      if (bt) { gv = s1.x; gi = i1; gx = s1.y; gy = s1.z; gz = s1.w; }
      bt = (s2.x > gv) || (s2.x == gv && i2 < gi);
      if (bt) { gv = s2.x; gi = i2; gx = s2.y; gy = s2.z; gz = s2.w; }
      bt = (s3.x > gv) || (s3.x == gv && i3 < gi);
      if (bt) { gv = s3.x; gi = i3; gx = s3.y; gy = s3.z; gz = s3.w; }
      cur = gi; cx = gx; cy = gy; cz = gz;
    }
    __syncthreads();
    for (int e = t; e < M_OUT; e += 256) fps_idx[b * M_OUT + e] = wlds[e];
  } else {
    // ---- conv: Z[b][n][o] = sum_c F[b][c][n] * W[o][c] ----
    float (*Bs)[68] = (float(*)[68])smem;          // [128][68]
    float (*As)[68] = (float(*)[68])(smem + 8704); // [32][68]
    const int bid = blockIdx.x - 8;
    const int n0 = (bid & 63) * 64;
    const int o0 = ((bid >> 6) & 3) * 64;
    const int b = bid >> 8;
    const int tid = threadIdx.x;
    for (int l = 0; l < 32; ++l) {
      int e = l * 256 + tid;
      int c = e & 127, oo = e >> 7;
      Bs[c][oo] = W[(o0 + oo) * CIN + c];
    }
    float acc[4][4] = {};
    const int tx = tid & 15, ty = tid >> 4;
    const float* Fb = F + b * CIN * N_PTS;
    for (int c0 = 0; c0 < CIN; c0 += 32) {
      __syncthreads();
      for (int l = 0; l < 8; ++l) {
        int e = l * 256 + tid;
        int nn = e & 63, cc = e >> 6;
        As[cc][nn] = Fb[(c0 + cc) * N_PTS + n0 + nn];
      }
      __syncthreads();
#pragma unroll
      for (int cc = 0; cc < 32; ++cc) {
        float4 a = *(const float4*)&As[cc][tx * 4];
        float4 w4 = *(const float4*)&Bs[c0 + cc][ty * 4];
        acc[0][0] += a.x * w4.x; acc[0][1] += a.x * w4.y; acc[0][2] += a.x * w4.z; acc[0][3] += a.x * w4.w;
        acc[1][0] += a.y * w4.x; acc[1][1] += a.y * w4.y; acc[1][2] += a.y * w4.z; acc[1][3] += a.y * w4.w;
        acc[2][0] += a.z * w4.x; acc[2][1] += a.z * w4.y; acc[2][2] += a.z * w4.z; acc[2][3] += a.z * w4.w;
        acc[3][0] += a.w * w4.x; acc[3][1] += a.w * w4.y; acc[3][2] += a.w * w4.z; acc[3][3] += a.w * w4.w;
      }
    }
    float* Zb = Z + (size_t)(b * N_PTS + n0) * COUT + o0;
#pragma unroll
    for (int i = 0; i < 4; ++i) {
      int nn = tx * 4 + i;
      float4 v = make_float4(acc[i][0], acc[i][1], acc[i][2], acc[i][3]);
      *(float4*)&Zb[(size_t)nn * COUT + ty * 4] = v;
    }
  }
}

// ---------------------------------------------------------------------------
// 2) FUSED ball query + gather/max-pool/BN/ReLU. Block = (batch, 8-center
//    m-tile); batch = blockIdx.x & 7 (XCD-locality heuristic: all blocks
//    gathering Z_b [4.2MB] land on one XCD's 4MiB L2). Phase 1: each of 4
//    waves runs the validated ballot-compaction ball query for 2 centers,
//    writing indices DIRECTLY into LDS (no global bidx round-trip). Phase 2:
//    the R8-validated pool body (int4 LDS index reads, 4 independent max
//    chains) + BN/ReLU epilogue (max commutes with the positive-scale
//    monotone affine + relu).
// ---------------------------------------------------------------------------
__global__ __launch_bounds__(256) void ballq_pool_kernel(
    const float* __restrict__ xyz, const int* __restrict__ fps_idx,
    const float* __restrict__ Z, const float* __restrict__ bias,
    const float* __restrict__ gamma, const float* __restrict__ beta,
    const float* __restrict__ rmean, const float* __restrict__ rvar,
    float* __restrict__ out) {
  __shared__ float T[COUT][9];
  __shared__ __align__(16) int sidx[8 * NS];
  const int b = blockIdx.x & 7;            // XCD-swizzled batch
  const int m0 = (blockIdx.x >> 3) * 8;    // 128 m-tiles of 8 per batch
  const int lane = threadIdx.x & 63, wv = threadIdx.x >> 6;
  const float* base = xyz + b * N_PTS * 3;
  // ---- phase 1: ball query for centers m0+2wv, m0+2wv+1 (validated logic,
  // output to LDS) ----
  {
#pragma clang fp contract(off)
    for (int cc2 = 0; cc2 < 2; ++cc2) {
      const int c = 2 * wv + cc2;
      const int cidx = fps_idx[b * M_OUT + m0 + c];
      const float cx = base[cidx * 3 + 0], cy = base[cidx * 3 + 1],
                  cz = base[cidx * 3 + 2];
      int* srow = sidx + c * NS;
      int cnt = 0, first = 0;
      for (int ch = 0; ch < N_PTS / 64 && cnt < NS; ++ch) {
        const int n = ch * 64 + lane;
        float dx = base[n * 3 + 0] - cx;
        float dy = base[n * 3 + 1] - cy;
        float dz = base[n * 3 + 2] - cz;
        float d = dx * dx + dy * dy;
        d = d + dz * dz;
        const bool inb = d < 0.1024f;  // f32(RADIUS^2)
        unsigned long long mask = __ballot(inb);
        if (cnt == 0 && mask) first = ch * 64 + (__ffsll(mask) - 1);
        const int pos = cnt + __popcll(mask & ((1ull << lane) - 1ull));
        if (inb && pos < NS) srow[pos] = n;
        cnt += (int)__popcll(mask);
      }
      if (lane >= cnt) srow[lane] = first;  // pad (center => cnt >= 1)
    }
  }
  __syncthreads();
  // ---- phase 2: gather + max-pool + BN + ReLU (R8-validated) ----
  const int o = threadIdx.x;
  const float sc = gamma[o] * (1.0f / sqrtf(rvar[o] + 1e-5f));
  const float bo = bias[o], mo = rmean[o], bt = beta[o];
  const float* Zb = Z + (size_t)b * N_PTS * COUT;
  for (int mi = 0; mi < 8; ++mi) {
    float b0 = -1e30f, b1 = -1e30f, b2 = -1e30f, b3 = -1e30f;
#pragma unroll
    for (int s = 0; s < NS; s += 4) {
      int4 iv = *(const int4*)&sidx[mi * NS + s];
      b0 = fmaxf(b0, Zb[(size_t)iv.x * COUT + o]);
      b1 = fmaxf(b1, Zb[(size_t)iv.y * COUT + o]);
      b2 = fmaxf(b2, Zb[(size_t)iv.z * COUT + o]);
      b3 = fmaxf(b3, Zb[(size_t)iv.w * COUT + o]);
    }
    float best = fmaxf(fmaxf(b0, b1), fmaxf(b2, b3));
    float t = best + bo;
    t = (t - mo) * sc + bt;
    T[o][mi] = fmaxf(t, 0.0f);
  }
  __syncthreads();
  for (int l = 0; l < 8; ++l) {
    int e = l * 256 + (int)threadIdx.x;
    int mm = e & 7, oo = e >> 3;
    out[(size_t)(b * COUT + oo) * M_OUT + m0 + mm] = T[oo][mm];
  }
}

extern "C" void kernel_launch(void* const* d_in, const int* in_sizes, int n_in,
                              void* d_out, int out_size, void* d_ws, size_t ws_size,
                              hipStream_t stream) {
  const float* xyz      = (const float*)d_in[0];
  const float* features = (const float*)d_in[1];
  const float* W        = (const float*)d_in[2];
  const float* bias     = (const float*)d_in[3];
  const float* gamma    = (const float*)d_in[4];
  const float* beta     = (const float*)d_in[5];
  const float* rmean    = (const float*)d_in[6];
  const float* rvar     = (const float*)d_in[7];
  float* out = (float*)d_out;

  char* ws = (char*)d_ws;
  int* fps  = (int*)ws;                                  // 32 KB
  float* Z  = (float*)(ws + (64 << 10) + (2 << 20));     // 33.5 MB

  fps_conv_kernel<<<8 + 2048, 256, 0, stream>>>(xyz, fps, features, W, Z);
  ballq_pool_kernel<<<B_SZ * (M_OUT / 8), 256, 0, stream>>>(
      xyz, fps, Z, bias, gamma, beta, rmean, rvar, out);
}